// Round 9
// baseline (98.860 us; speedup 1.0000x reference)
//
#include <hip/hip_runtime.h>

// Linear attention, fp32. N=8, L=S=8192, H=8, D=Dv=32.
// out[n,l,h,v] = (sum_d phiQ[l,d]*KV[d][v]) * 1/(sum_d phiQ[l,d]*Ksum[d] + 1e-6)
// where KV[d][v] = sum_s phiK[s,d]*values[s,v]  (the /S and *S of the reference
// cancel exactly: S is a power of two).
//
// R9: phase2 = R8 + forced KV register residency. R8's VGPR_Count=64 proved
// the compiler rematerialized the kvc loads inside the row loop (live-set
// math needs ~90) -> per-row L2 re-fetch latency = the 61% VALU-idle time.
// Fix: asm "+v" pins make kvc/ks opaque (cannot re-load), and
// __launch_bounds__(256,2) lifts the register budget.

#define N_      8
#define L_      8192
#define S_      8192
#define H_      8
#define D_      32
#define NH_     64            // N*H
#define CHUNKS_ 32            // phase-1 s-chunks per (n,h)
#define ROWS_   (S_ / CHUNKS_) // 256 rows per block
#define TILE_   64            // staged rows per LDS tile
#define KVE_    (D_ * D_)     // 1024
#define PKS_    (KVE_ + D_)   // 1056 floats: KV + Ksum
#define RPB_    32            // phase2: (n,l)-rows per block

__device__ __forceinline__ float phi_f(float x) {
    // elu(x)+1 : x>0 -> x+1 ; else exp(x)
    return x > 0.f ? x + 1.f : __expf(x);
}

#define PIN4(v4) asm volatile("" : "+v"((v4).x), "+v"((v4).y), "+v"((v4).z), "+v"((v4).w))

// ---------------- Phase 1: KV + Ksum accumulation over s ----------------
template <bool ATOMIC>
__global__ __launch_bounds__(256) void la_phase1(
    const float* __restrict__ keys, const float* __restrict__ values,
    float* __restrict__ outp /* ATOMIC ? kvfinal[NH][PKS] : partials[NH][CHUNKS][PKS] */)
{
    __shared__ float kT[TILE_][D_];
    __shared__ float vT[TILE_][D_];
    const int nh    = blockIdx.x;   // 0..63
    const int chunk = blockIdx.y;   // 0..31
    const int n = nh >> 3, h = nh & 7;
    const int t  = threadIdx.x;
    const int d  = t & 31;          // this thread's K-dim
    const int vg = t >> 5;          // v-group: 4 consecutive v columns
    const size_t rs = (size_t)H_ * D_;   // 256 floats per (n,s) row
    const float* kbase = keys   + ((size_t)n * S_) * rs + (size_t)h * D_;
    const float* vbase = values + ((size_t)n * S_) * rs + (size_t)h * D_;
    const int s0 = chunk * ROWS_;

    float a0 = 0.f, a1 = 0.f, a2 = 0.f, a3 = 0.f, ksum = 0.f;

    for (int tb = 0; tb < ROWS_; tb += TILE_) {
        __syncthreads();
        // stage 64 rows of K (phi applied) and V; coalesced: 8 threads per row
#pragma unroll
        for (int i = 0; i < 2; ++i) {
            const int f   = t + i * 256;      // 0..511
            const int row = f >> 3;           // 0..63
            const int col = (f & 7) << 2;     // 0,4,...,28
            const size_t g = (size_t)(s0 + tb + row) * rs + col;
            const float4 k4 = *(const float4*)(kbase + g);
            const float4 v4 = *(const float4*)(vbase + g);
            *(float4*)&kT[row][col] =
                make_float4(phi_f(k4.x), phi_f(k4.y), phi_f(k4.z), phi_f(k4.w));
            *(float4*)&vT[row][col] = v4;
        }
        __syncthreads();
#pragma unroll 16
        for (int s = 0; s < TILE_; ++s) {
            const float  kk = kT[s][d];                        // b32, lanes->banks 0..31
            const float4 vv = *(const float4*)&vT[s][vg << 2]; // broadcast b128
            a0 = fmaf(kk, vv.x, a0);
            a1 = fmaf(kk, vv.y, a1);
            a2 = fmaf(kk, vv.z, a2);
            a3 = fmaf(kk, vv.w, a3);
            ksum += kk;   // identical across vg groups; only vg==0 stores it
        }
    }

    const int o = d * D_ + (vg << 2);
    if (ATOMIC) {
        float* p = outp + (size_t)nh * PKS_;
        atomicAdd(&p[o + 0], a0);
        atomicAdd(&p[o + 1], a1);
        atomicAdd(&p[o + 2], a2);
        atomicAdd(&p[o + 3], a3);
        if (vg == 0) atomicAdd(&p[KVE_ + d], ksum);
    } else {
        float* p = outp + ((size_t)nh * CHUNKS_ + chunk) * PKS_;
        *(float4*)&p[o] = make_float4(a0, a1, a2, a3);
        if (vg == 0) p[KVE_ + d] = ksum;
    }
}

// ---------------- Phase 1b: deterministic 32-way partial reduce ----------------
__global__ __launch_bounds__(256) void la_reduce(
    const float* __restrict__ partials, float* __restrict__ kvf)
{
    const int nh = blockIdx.x;
    for (int e = threadIdx.x; e < PKS_; e += 256) {
        const float* p = partials + (size_t)nh * CHUNKS_ * PKS_ + e;
        float s = 0.f;
#pragma unroll
        for (int c = 0; c < CHUNKS_; ++c) s += p[(size_t)c * PKS_];
        kvf[(size_t)nh * PKS_ + e] = s;
    }
}

__global__ void la_zero(float* __restrict__ p, int nelem) {
    const int i = blockIdx.x * 256 + threadIdx.x;
    if (i < nelem) p[i] = 0.f;
}

// ---------------- Phase 2: out = (phiQ . KV) * z (LDS-free, KV pinned) ------
// Block = 32 consecutive (n,l) rows x ALL 8 heads; wave w owns rows 8w..8w+7.
// Lane: h = lane>>3, vs = lane&7. Per d-chunk (8 d's) the thread's KV slice
// (8 float4) is loaded from L2-hot kvf ONCE and pinned in VGPRs via asm, then
// reused across 8 rows. Q read from global (vs-lane broadcast merges in L1);
// phi recomputed per use. 1KB dense wave-stores.
__global__ __launch_bounds__(256, 2) void la_phase2(
    const float* __restrict__ queries, const float* __restrict__ kvf,
    float* __restrict__ out)
{
    const int t = threadIdx.x, lane = t & 63, w = t >> 6;
    const int h = lane >> 3, vs = lane & 7;
    const size_t rowg0 = (size_t)blockIdx.x * RPB_;   // global (n,l)-row base
    const int n = (int)(rowg0 >> 13);                 // rowg0 / L_
    const float* kvb = kvf + (size_t)(n * 8 + h) * PKS_;
    const float4* qg = (const float4*)(queries + rowg0 * 256);
    float4* og = (float4*)(out + rowg0 * 256);
    const int r0 = w << 3;

    float acc[8][4], dot[8];
#pragma unroll
    for (int r = 0; r < 8; ++r) {
        dot[r] = 0.f;
#pragma unroll
        for (int j = 0; j < 4; ++j) acc[r][j] = 0.f;
    }

#pragma unroll
    for (int c = 0; c < 4; ++c) {                 // d-chunk: d in [8c, 8c+8)
        float4 kvc[8];                            // thread's KV slice: 32 regs
#pragma unroll
        for (int j = 0; j < 8; ++j)
            kvc[j] = *(const float4*)(kvb + ((c << 3) + j) * D_ + (vs << 2));
        float4 ksA = *(const float4*)(kvb + KVE_ + (c << 3));
        float4 ksB = *(const float4*)(kvb + KVE_ + (c << 3) + 4);
        // pin: values become opaque -> compiler cannot rematerialize the loads
#pragma unroll
        for (int j = 0; j < 8; ++j) PIN4(kvc[j]);
        PIN4(ksA); PIN4(ksB);

#pragma unroll
        for (int r = 0; r < 8; ++r) {
            float4 q0 = qg[(size_t)(r0 + r) * 64 + (h << 3) + (c << 1)];
            float4 q1 = qg[(size_t)(r0 + r) * 64 + (h << 3) + (c << 1) + 1];
            q0 = make_float4(phi_f(q0.x), phi_f(q0.y), phi_f(q0.z), phi_f(q0.w));
            q1 = make_float4(phi_f(q1.x), phi_f(q1.y), phi_f(q1.z), phi_f(q1.w));
            float dt = dot[r];
            dt = fmaf(q0.x, ksA.x, dt); dt = fmaf(q0.y, ksA.y, dt);
            dt = fmaf(q0.z, ksA.z, dt); dt = fmaf(q0.w, ksA.w, dt);
            dt = fmaf(q1.x, ksB.x, dt); dt = fmaf(q1.y, ksB.y, dt);
            dt = fmaf(q1.z, ksB.z, dt); dt = fmaf(q1.w, ksB.w, dt);
            dot[r] = dt;
            float a0 = acc[r][0], a1 = acc[r][1], a2 = acc[r][2], a3 = acc[r][3];
            a0 = fmaf(q0.x, kvc[0].x, a0); a1 = fmaf(q0.x, kvc[0].y, a1);
            a2 = fmaf(q0.x, kvc[0].z, a2); a3 = fmaf(q0.x, kvc[0].w, a3);
            a0 = fmaf(q0.y, kvc[1].x, a0); a1 = fmaf(q0.y, kvc[1].y, a1);
            a2 = fmaf(q0.y, kvc[1].z, a2); a3 = fmaf(q0.y, kvc[1].w, a3);
            a0 = fmaf(q0.z, kvc[2].x, a0); a1 = fmaf(q0.z, kvc[2].y, a1);
            a2 = fmaf(q0.z, kvc[2].z, a2); a3 = fmaf(q0.z, kvc[2].w, a3);
            a0 = fmaf(q0.w, kvc[3].x, a0); a1 = fmaf(q0.w, kvc[3].y, a1);
            a2 = fmaf(q0.w, kvc[3].z, a2); a3 = fmaf(q0.w, kvc[3].w, a3);
            a0 = fmaf(q1.x, kvc[4].x, a0); a1 = fmaf(q1.x, kvc[4].y, a1);
            a2 = fmaf(q1.x, kvc[4].z, a2); a3 = fmaf(q1.x, kvc[4].w, a3);
            a0 = fmaf(q1.y, kvc[5].x, a0); a1 = fmaf(q1.y, kvc[5].y, a1);
            a2 = fmaf(q1.y, kvc[5].z, a2); a3 = fmaf(q1.y, kvc[5].w, a3);
            a0 = fmaf(q1.z, kvc[6].x, a0); a1 = fmaf(q1.z, kvc[6].y, a1);
            a2 = fmaf(q1.z, kvc[6].z, a2); a3 = fmaf(q1.z, kvc[6].w, a3);
            a0 = fmaf(q1.w, kvc[7].x, a0); a1 = fmaf(q1.w, kvc[7].y, a1);
            a2 = fmaf(q1.w, kvc[7].z, a2); a3 = fmaf(q1.w, kvc[7].w, a3);
            acc[r][0] = a0; acc[r][1] = a1; acc[r][2] = a2; acc[r][3] = a3;
        }
    }

#pragma unroll
    for (int r = 0; r < 8; ++r) {
        const float z = 1.f / (dot[r] + 1e-6f);
        // lanes 0..63 cover float4 0..63 of the row -> 1KB dense store
        og[(size_t)(r0 + r) * 64 + lane] =
            make_float4(acc[r][0] * z, acc[r][1] * z, acc[r][2] * z, acc[r][3] * z);
    }
}

extern "C" void kernel_launch(void* const* d_in, const int* in_sizes, int n_in,
                              void* d_out, int out_size, void* d_ws, size_t ws_size,
                              hipStream_t stream)
{
    const float* queries = (const float*)d_in[0];
    const float* keys    = (const float*)d_in[1];
    const float* values  = (const float*)d_in[2];
    float* out = (float*)d_out;
    float* ws  = (float*)d_ws;

    const size_t partial_elems = (size_t)NH_ * CHUNKS_ * PKS_; // 2,162,688 floats
    const size_t final_elems   = (size_t)NH_ * PKS_;           // 67,584 floats
    const dim3 blk(256);
    const int p2_blocks = (N_ * L_) / RPB_;                    // 2048

    if (ws_size >= (partial_elems + final_elems) * sizeof(float)) {
        // deterministic two-stage reduction
        float* partials = ws;
        float* kvf      = ws + partial_elems;
        la_phase1<false><<<dim3(NH_, CHUNKS_), blk, 0, stream>>>(keys, values, partials);
        la_reduce<<<dim3(NH_), blk, 0, stream>>>(partials, kvf);
        la_phase2<<<dim3(p2_blocks), blk, 0, stream>>>(queries, kvf, out);
    } else {
        // fallback: atomic accumulation into zeroed final buffer
        float* kvf = ws;
        const int nz = (int)final_elems;
        la_zero<<<dim3((nz + 255) / 256), blk, 0, stream>>>(kvf, nz);
        la_phase1<true><<<dim3(NH_, CHUNKS_), blk, 0, stream>>>(keys, values, kvf);
        la_phase2<<<dim3(p2_blocks), blk, 0, stream>>>(queries, kvf, out);
    }
}

// Round 10
// 80.865 us; speedup vs baseline: 1.2225x; 1.2225x over previous
//
#include <hip/hip_runtime.h>
#include <hip/hip_bf16.h>

// Linear attention, fp32. N=8, L=S=8192, H=8, D=Dv=32.
// out[n,l,h,v] = (sum_d phiQ[l,d]*KV[d][v]) * 1/(sum_d phiQ[l,d]*Ksum[d] + 1e-6)
// where KV[d][v] = sum_s phiK[s,d]*values[s,v]  (the /S and *S of the reference
// cancel exactly: S is a power of two).
//
// R10: phase2 moved to MFMA with split-bf16 (hi+lo, 3-term product, fp32
// accum; error ~1e-7 on outputs thanks to the positive-sum denominator).
// Rationale: R1-R9's fp32 formulations all landed 61-88us because the 4KB KV
// operand must be replicated per lane on the VALU path (re-fetch or register
// blowup) and phi/addr VALU work (~33us busy) can't hide the latency. MFMA
// shares KV across 64 lanes in the matrix pipe: per 16-row tile x head =
// 6 MFMAs, 8 VMEM, ~150 VALU. KV is pre-split/transposed to bf16 in la_reduce.

#define N_      8
#define L_      8192
#define S_      8192
#define H_      8
#define D_      32
#define NH_     64            // N*H
#define CHUNKS_ 32            // phase-1 s-chunks per (n,h)
#define ROWS_   (S_ / CHUNKS_) // 256 rows per block
#define TILE_   64            // staged rows per LDS tile
#define KVE_    (D_ * D_)     // 1024
#define PKS_    (KVE_ + D_)   // 1056 floats: KV + Ksum

typedef short short8 __attribute__((ext_vector_type(8)));
typedef float f32x4  __attribute__((ext_vector_type(4)));

__device__ __forceinline__ float phi_f(float x) {
    // elu(x)+1 : x>0 -> x+1 ; else exp(x)
    return x > 0.f ? x + 1.f : __expf(x);
}

__device__ __forceinline__ void split_bf16(float x, short& hi, short& lo) {
    __hip_bfloat16 hb = __float2bfloat16(x);        // RNE
    const float xh = __bfloat162float(hb);
    __hip_bfloat16 lb = __float2bfloat16(x - xh);
    __builtin_memcpy(&hi, &hb, 2);
    __builtin_memcpy(&lo, &lb, 2);
}

// ---------------- Phase 1: KV + Ksum accumulation over s ----------------
template <bool ATOMIC>
__global__ __launch_bounds__(256) void la_phase1(
    const float* __restrict__ keys, const float* __restrict__ values,
    float* __restrict__ outp /* ATOMIC ? kvfinal[NH][PKS] : partials[NH][CHUNKS][PKS] */)
{
    __shared__ float kT[TILE_][D_];
    __shared__ float vT[TILE_][D_];
    const int nh    = blockIdx.x;   // 0..63
    const int chunk = blockIdx.y;   // 0..31
    const int n = nh >> 3, h = nh & 7;
    const int t  = threadIdx.x;
    const int d  = t & 31;          // this thread's K-dim
    const int vg = t >> 5;          // v-group: 4 consecutive v columns
    const size_t rs = (size_t)H_ * D_;   // 256 floats per (n,s) row
    const float* kbase = keys   + ((size_t)n * S_) * rs + (size_t)h * D_;
    const float* vbase = values + ((size_t)n * S_) * rs + (size_t)h * D_;
    const int s0 = chunk * ROWS_;

    float a0 = 0.f, a1 = 0.f, a2 = 0.f, a3 = 0.f, ksum = 0.f;

    for (int tb = 0; tb < ROWS_; tb += TILE_) {
        __syncthreads();
        // stage 64 rows of K (phi applied) and V; coalesced: 8 threads per row
#pragma unroll
        for (int i = 0; i < 2; ++i) {
            const int f   = t + i * 256;      // 0..511
            const int row = f >> 3;           // 0..63
            const int col = (f & 7) << 2;     // 0,4,...,28
            const size_t g = (size_t)(s0 + tb + row) * rs + col;
            const float4 k4 = *(const float4*)(kbase + g);
            const float4 v4 = *(const float4*)(vbase + g);
            *(float4*)&kT[row][col] =
                make_float4(phi_f(k4.x), phi_f(k4.y), phi_f(k4.z), phi_f(k4.w));
            *(float4*)&vT[row][col] = v4;
        }
        __syncthreads();
#pragma unroll 16
        for (int s = 0; s < TILE_; ++s) {
            const float  kk = kT[s][d];                        // b32, lanes->banks 0..31
            const float4 vv = *(const float4*)&vT[s][vg << 2]; // broadcast b128
            a0 = fmaf(kk, vv.x, a0);
            a1 = fmaf(kk, vv.y, a1);
            a2 = fmaf(kk, vv.z, a2);
            a3 = fmaf(kk, vv.w, a3);
            ksum += kk;   // identical across vg groups; only vg==0 stores it
        }
    }

    const int o = d * D_ + (vg << 2);
    if (ATOMIC) {
        float* p = outp + (size_t)nh * PKS_;
        atomicAdd(&p[o + 0], a0);
        atomicAdd(&p[o + 1], a1);
        atomicAdd(&p[o + 2], a2);
        atomicAdd(&p[o + 3], a3);
        if (vg == 0) atomicAdd(&p[KVE_ + d], ksum);
    } else {
        float* p = outp + ((size_t)nh * CHUNKS_ + chunk) * PKS_;
        *(float4*)&p[o] = make_float4(a0, a1, a2, a3);
        if (vg == 0) p[KVE_ + d] = ksum;
    }
}

// ---- Phase 1b: deterministic 32-way reduce + split-bf16 transpose ----
// kvThi/kvTlo: [NH][32v][32d] bf16 (transposed so phase2 B-frag is one b128);
// ksumf: [NH][32] fp32 for the fp32 dot.
__global__ __launch_bounds__(256) void la_reduce(
    const float* __restrict__ partials,
    short* __restrict__ kvThi, short* __restrict__ kvTlo,
    float* __restrict__ ksumf)
{
    const int nh = blockIdx.x;
    for (int e = threadIdx.x; e < PKS_; e += 256) {
        const float* p = partials + (size_t)nh * CHUNKS_ * PKS_ + e;
        float s = 0.f;
#pragma unroll
        for (int c = 0; c < CHUNKS_; ++c) s += p[(size_t)c * PKS_];
        if (e < KVE_) {
            const int d = e >> 5, v = e & 31;
            short hi, lo; split_bf16(s, hi, lo);
            kvThi[nh * KVE_ + v * D_ + d] = hi;
            kvTlo[nh * KVE_ + v * D_ + d] = lo;
        } else {
            ksumf[nh * D_ + (e - KVE_)] = s;
        }
    }
}

// atomic-path variant: same split/transpose from a finished kvf buffer
__global__ __launch_bounds__(256) void la_convert(
    const float* __restrict__ kvf,
    short* __restrict__ kvThi, short* __restrict__ kvTlo,
    float* __restrict__ ksumf)
{
    const int nh = blockIdx.x;
    for (int e = threadIdx.x; e < PKS_; e += 256) {
        const float s = kvf[(size_t)nh * PKS_ + e];
        if (e < KVE_) {
            const int d = e >> 5, v = e & 31;
            short hi, lo; split_bf16(s, hi, lo);
            kvThi[nh * KVE_ + v * D_ + d] = hi;
            kvTlo[nh * KVE_ + v * D_ + d] = lo;
        } else {
            ksumf[nh * D_ + (e - KVE_)] = s;
        }
    }
}

__global__ void la_zero(float* __restrict__ p, int nelem) {
    const int i = blockIdx.x * 256 + threadIdx.x;
    if (i < nelem) p[i] = 0.f;
}

// ---------------- Phase 2: MFMA split-bf16 ----------------
// Wave-task = (16-row tile, h): C[16x32] = phiQ[16x32] @ KV[32x32] via
// 2 v-tiles x 3 split-term mfma_f32_16x16x32_bf16. A-frag: row=lane&15,
// k=(lane>>4)*8+e (any k-permutation cancels: A,B share the mapping).
// D (m89-verified): col=lane&15, row=(lane>>4)*4+reg. dot on fp32 VALU.
__global__ __launch_bounds__(256) void la_phase2(
    const float* __restrict__ queries,
    const short* __restrict__ kvThi, const short* __restrict__ kvTlo,
    const float* __restrict__ ksumf, float* __restrict__ out)
{
    const int t = threadIdx.x, lane = t & 63, w = t >> 6;
    const int wt = blockIdx.x * 4 + w;      // 0..32767
    const int h  = wt & 7;
    const int rt = wt >> 3;                 // 16-row tile id, 0..4095
    const size_t rowg0 = (size_t)rt * 16;   // global (n,l)-row base
    const int n = (int)(rowg0 >> 13);
    const int nh = n * 8 + h;
    const int row_l = lane & 15;            // A-row / B-col
    const int kg    = lane >> 4;            // k-group: k = kg*8 + e

    // ---- A: load 8 fp32 q, phi, keep fp32 for dot, split to bf16 hi/lo ----
    const float* qp = queries + (rowg0 + row_l) * 256 + h * D_ + kg * 8;
    float qa[8];
    {
        const float4 qA = *(const float4*)(qp);
        const float4 qB = *(const float4*)(qp + 4);
        qa[0] = phi_f(qA.x); qa[1] = phi_f(qA.y); qa[2] = phi_f(qA.z); qa[3] = phi_f(qA.w);
        qa[4] = phi_f(qB.x); qa[5] = phi_f(qB.y); qa[6] = phi_f(qB.z); qa[7] = phi_f(qB.w);
    }
    short8 ahi, alo;
#pragma unroll
    for (int e = 0; e < 8; ++e) {
        short hs, ls; split_bf16(qa[e], hs, ls);
        ahi[e] = hs; alo[e] = ls;
    }

    // ---- B: one short8 per (vtile, hi/lo) from transposed bf16 KV ----
    const short* bh = kvThi + (size_t)nh * KVE_;
    const short* bl = kvTlo + (size_t)nh * KVE_;
    const short8 bh0 = *(const short8*)(bh + (row_l     ) * D_ + kg * 8);
    const short8 bh1 = *(const short8*)(bh + (row_l + 16) * D_ + kg * 8);
    const short8 bl0 = *(const short8*)(bl + (row_l     ) * D_ + kg * 8);
    const short8 bl1 = *(const short8*)(bl + (row_l + 16) * D_ + kg * 8);

    // ---- 6 MFMAs: C = Alo*Bhi + Ahi*Blo + Ahi*Bhi (fp32 accum) ----
    f32x4 c0 = {0.f, 0.f, 0.f, 0.f}, c1 = {0.f, 0.f, 0.f, 0.f};
    c0 = __builtin_amdgcn_mfma_f32_16x16x32_bf16(alo, bh0, c0, 0, 0, 0);
    c0 = __builtin_amdgcn_mfma_f32_16x16x32_bf16(ahi, bl0, c0, 0, 0, 0);
    c0 = __builtin_amdgcn_mfma_f32_16x16x32_bf16(ahi, bh0, c0, 0, 0, 0);
    c1 = __builtin_amdgcn_mfma_f32_16x16x32_bf16(alo, bh1, c1, 0, 0, 0);
    c1 = __builtin_amdgcn_mfma_f32_16x16x32_bf16(ahi, bl1, c1, 0, 0, 0);
    c1 = __builtin_amdgcn_mfma_f32_16x16x32_bf16(ahi, bh1, c1, 0, 0, 0);

    // ---- dot = phiQ . Ksum in fp32; reduce the 4 k-groups per row ----
    const float* ksp = ksumf + nh * D_ + kg * 8;
    float dt;
    {
        const float4 kA = *(const float4*)(ksp);
        const float4 kB = *(const float4*)(ksp + 4);
        dt = qa[0] * kA.x;
        dt = fmaf(qa[1], kA.y, dt); dt = fmaf(qa[2], kA.z, dt);
        dt = fmaf(qa[3], kA.w, dt); dt = fmaf(qa[4], kB.x, dt);
        dt = fmaf(qa[5], kB.y, dt); dt = fmaf(qa[6], kB.z, dt);
        dt = fmaf(qa[7], kB.w, dt);
    }
    dt += __shfl_xor(dt, 16);
    dt += __shfl_xor(dt, 32);   // all lanes now hold dot[row_l]

    // ---- normalize + store: row' = kg*4 + r, col = row_l (m89 layout) ----
    float* ob = out + rowg0 * 256 + h * D_ + row_l;
#pragma unroll
    for (int r = 0; r < 4; ++r) {
        const int rowp = kg * 4 + r;
        const float drow = __shfl(dt, rowp);          // lane rowp holds dot[rowp]
        const float z = __builtin_amdgcn_rcpf(drow + 1e-6f);
        ob[(size_t)rowp * 256]      = c0[r] * z;
        ob[(size_t)rowp * 256 + 16] = c1[r] * z;
    }
}

extern "C" void kernel_launch(void* const* d_in, const int* in_sizes, int n_in,
                              void* d_out, int out_size, void* d_ws, size_t ws_size,
                              hipStream_t stream)
{
    const float* queries = (const float*)d_in[0];
    const float* keys    = (const float*)d_in[1];
    const float* values  = (const float*)d_in[2];
    float* out = (float*)d_out;
    float* ws  = (float*)d_ws;

    const size_t partial_elems = (size_t)NH_ * CHUNKS_ * PKS_; // 2,162,688 floats
    const size_t split_elems   = (size_t)NH_ * KVE_;           // per hi/lo, in shorts
    const size_t split_floats  = split_elems / 2;              // 32,768 float-slots each
    const size_t ksum_floats   = (size_t)NH_ * D_;             // 2,048
    const dim3 blk(256);
    const int p2_blocks = (N_ * L_ * H_) / 16 / 4;             // 8192

    if (ws_size >= (partial_elems + 2 * split_floats + ksum_floats) * sizeof(float)) {
        // deterministic two-stage reduction + split-bf16 conversion
        float* partials = ws;
        short* kvThi = (short*)(ws + partial_elems);
        short* kvTlo = kvThi + split_elems;
        float* ksumf = (float*)(kvTlo + split_elems);
        la_phase1<false><<<dim3(NH_, CHUNKS_), blk, 0, stream>>>(keys, values, partials);
        la_reduce<<<dim3(NH_), blk, 0, stream>>>(partials, kvThi, kvTlo, ksumf);
        la_phase2<<<dim3(p2_blocks), blk, 0, stream>>>(queries, kvThi, kvTlo, ksumf, out);
    } else {
        // fallback: atomic accumulation into zeroed kvf, then convert
        float* kvf = ws;
        short* kvThi = (short*)(ws + (size_t)NH_ * PKS_);
        short* kvTlo = kvThi + split_elems;
        float* ksumf = (float*)(kvTlo + split_elems);
        const int nz = (int)((size_t)NH_ * PKS_);
        la_zero<<<dim3((nz + 255) / 256), blk, 0, stream>>>(kvf, nz);
        la_phase1<true><<<dim3(NH_, CHUNKS_), blk, 0, stream>>>(keys, values, kvf);
        la_convert<<<dim3(NH_), blk, 0, stream>>>(kvf, kvThi, kvTlo, ksumf);
        la_phase2<<<dim3(p2_blocks), blk, 0, stream>>>(queries, kvThi, kvTlo, ksumf, out);
    }
}

// Round 11
// 80.175 us; speedup vs baseline: 1.2330x; 1.0086x over previous
//
#include <hip/hip_runtime.h>
#include <hip/hip_bf16.h>

// Linear attention, fp32. N=8, L=S=8192, H=8, D=Dv=32.
// out[n,l,h,v] = (sum_d phiQ[l,d]*KV[d][v]) * 1/(sum_d phiQ[l,d]*Ksum[d] + 1e-6)
// where KV[d][v] = sum_s phiK[s,d]*values[s,v]  (the /S and *S of the reference
// cancel exactly: S is a power of two).
//
// R11: phase1 restructured for LDS-instruction economy. R10's profile proved
// phase1 is LDS-issue bound (57us even fully L3-warm): 512 ds-ops/thread for
// 5-FMA/2-op intensity. New mapping: thread=(wave=8d, vg=4v, ss=s-slice);
// per s: 3x ds_read_b128 -> 32 FMA (96 ds-ops/thread, 5.3x fewer). Rows
// padded to 36 floats (bank shift 4/s): K-read = 8 addrs x 8-lane broadcast
// covering all 32 banks; V-read at the 1024B/instr structural floor.
// Phase2 = R10's split-bf16 MFMA (passed, absmax 2.4e-4).

#define N_      8
#define L_      8192
#define S_      8192
#define H_      8
#define D_      32
#define NH_     64            // N*H
#define CHUNKS_ 32            // phase-1 s-chunks per (n,h)
#define ROWS_   (S_ / CHUNKS_) // 256 rows per block
#define TILE_   64            // staged rows per LDS tile
#define KVE_    (D_ * D_)     // 1024
#define PKS_    (KVE_ + D_)   // 1056 floats: KV + Ksum

typedef short short8 __attribute__((ext_vector_type(8)));
typedef float f32x4  __attribute__((ext_vector_type(4)));

__device__ __forceinline__ float phi_f(float x) {
    // elu(x)+1 : x>0 -> x+1 ; else exp(x)
    return x > 0.f ? x + 1.f : __expf(x);
}

__device__ __forceinline__ void split_bf16(float x, short& hi, short& lo) {
    __hip_bfloat16 hb = __float2bfloat16(x);        // RNE
    const float xh = __bfloat162float(hb);
    __hip_bfloat16 lb = __float2bfloat16(x - xh);
    __builtin_memcpy(&hi, &hb, 2);
    __builtin_memcpy(&lo, &lb, 2);
}

// ---------------- Phase 1: KV + Ksum accumulation over s ----------------
// Thread: dg = wave (8 d's), vg = lane&7 (4 v's), ss = lane>>3 (s-slice).
// Per tile of 64 s: thread handles s = ss+8i, i=0..7; 3 b128 LDS reads/s.
template <bool ATOMIC>
__global__ __launch_bounds__(256) void la_phase1(
    const float* __restrict__ keys, const float* __restrict__ values,
    float* __restrict__ outp /* ATOMIC ? kvfinal[NH][PKS] : partials[NH][CHUNKS][PKS] */)
{
    __shared__ float4 kT4[TILE_][9];   // row stride 36 floats (bank shift 4/s)
    __shared__ float4 vT4[TILE_][9];
    const int nh    = blockIdx.x;   // 0..63
    const int chunk = blockIdx.y;   // 0..31
    const int n = nh >> 3, h = nh & 7;
    const int t = threadIdx.x, lane = t & 63;
    const int dg = t >> 6;          // wave id: d-block [8dg, 8dg+8)
    const int vg = lane & 7;        // v-group: [4vg, 4vg+4)
    const int ss = lane >> 3;       // s-slice within tile
    const size_t rs = (size_t)H_ * D_;   // 256 floats per (n,s) row
    const float* kbase = keys   + ((size_t)n * S_) * rs + (size_t)h * D_;
    const float* vbase = values + ((size_t)n * S_) * rs + (size_t)h * D_;
    const int s0 = chunk * ROWS_;

    float acc[8][4];
    float ksum[8];
#pragma unroll
    for (int j = 0; j < 8; ++j) {
        ksum[j] = 0.f;
#pragma unroll
        for (int v = 0; v < 4; ++v) acc[j][v] = 0.f;
    }

    for (int tb = 0; tb < ROWS_; tb += TILE_) {
        __syncthreads();
        // stage 64 rows of K (phi applied) and V; coalesced: 8 threads per row
#pragma unroll
        for (int i = 0; i < 2; ++i) {
            const int f   = t + i * 256;      // 0..511
            const int row = f >> 3;           // 0..63
            const int c4  = f & 7;            // float4 col 0..7
            const size_t g = (size_t)(s0 + tb + row) * rs + (c4 << 2);
            const float4 k4 = *(const float4*)(kbase + g);
            kT4[row][c4] = make_float4(phi_f(k4.x), phi_f(k4.y), phi_f(k4.z), phi_f(k4.w));
            vT4[row][c4] = *(const float4*)(vbase + g);
        }
        __syncthreads();
#pragma unroll
        for (int i = 0; i < 8; ++i) {
            const int s = ss + (i << 3);
            const float4 k0 = kT4[s][(dg << 1) + 0];   // d = 8dg..8dg+3
            const float4 k1 = kT4[s][(dg << 1) + 1];   // d = 8dg+4..8dg+7
            const float4 vv = vT4[s][vg];              // v = 4vg..4vg+3
            const float kk[8] = {k0.x, k0.y, k0.z, k0.w, k1.x, k1.y, k1.z, k1.w};
#pragma unroll
            for (int j = 0; j < 8; ++j) {
                acc[j][0] = fmaf(kk[j], vv.x, acc[j][0]);
                acc[j][1] = fmaf(kk[j], vv.y, acc[j][1]);
                acc[j][2] = fmaf(kk[j], vv.z, acc[j][2]);
                acc[j][3] = fmaf(kk[j], vv.w, acc[j][3]);
                ksum[j] += kk[j];   // redundant across vg; vg==0's value used
            }
        }
    }

    // reduce over ss (lane bits 3..5) via shfl butterfly; deterministic
#pragma unroll
    for (int j = 0; j < 8; ++j) {
#pragma unroll
        for (int v = 0; v < 4; ++v) {
            float x = acc[j][v];
            x += __shfl_xor(x, 8);
            x += __shfl_xor(x, 16);
            x += __shfl_xor(x, 32);
            acc[j][v] = x;
        }
        float y = ksum[j];
        y += __shfl_xor(y, 8);
        y += __shfl_xor(y, 16);
        y += __shfl_xor(y, 32);
        ksum[j] = y;
    }

    if (ss == 0) {
        if (ATOMIC) {
            float* p = outp + (size_t)nh * PKS_;
#pragma unroll
            for (int j = 0; j < 8; ++j) {
                const int o = ((dg << 3) + j) * D_ + (vg << 2);
                atomicAdd(&p[o + 0], acc[j][0]);
                atomicAdd(&p[o + 1], acc[j][1]);
                atomicAdd(&p[o + 2], acc[j][2]);
                atomicAdd(&p[o + 3], acc[j][3]);
            }
            if (vg == 0)
#pragma unroll
                for (int j = 0; j < 8; ++j) atomicAdd(&p[KVE_ + (dg << 3) + j], ksum[j]);
        } else {
            float* p = outp + ((size_t)nh * CHUNKS_ + chunk) * PKS_;
#pragma unroll
            for (int j = 0; j < 8; ++j) {
                const int o = ((dg << 3) + j) * D_ + (vg << 2);
                *(float4*)&p[o] = make_float4(acc[j][0], acc[j][1], acc[j][2], acc[j][3]);
            }
            if (vg == 0)
#pragma unroll
                for (int j = 0; j < 8; ++j) p[KVE_ + (dg << 3) + j] = ksum[j];
        }
    }
}

// ---- Phase 1b: deterministic 32-way reduce + split-bf16 transpose ----
// kvThi/kvTlo: [NH][32v][32d] bf16 (transposed so phase2 B-frag is one b128);
// ksumf: [NH][32] fp32 for the fp32 dot.
__global__ __launch_bounds__(256) void la_reduce(
    const float* __restrict__ partials,
    short* __restrict__ kvThi, short* __restrict__ kvTlo,
    float* __restrict__ ksumf)
{
    const int nh = blockIdx.x;
    for (int e = threadIdx.x; e < PKS_; e += 256) {
        const float* p = partials + (size_t)nh * CHUNKS_ * PKS_ + e;
        float s = 0.f;
#pragma unroll
        for (int c = 0; c < CHUNKS_; ++c) s += p[(size_t)c * PKS_];
        if (e < KVE_) {
            const int d = e >> 5, v = e & 31;
            short hi, lo; split_bf16(s, hi, lo);
            kvThi[nh * KVE_ + v * D_ + d] = hi;
            kvTlo[nh * KVE_ + v * D_ + d] = lo;
        } else {
            ksumf[nh * D_ + (e - KVE_)] = s;
        }
    }
}

// atomic-path variant: same split/transpose from a finished kvf buffer
__global__ __launch_bounds__(256) void la_convert(
    const float* __restrict__ kvf,
    short* __restrict__ kvThi, short* __restrict__ kvTlo,
    float* __restrict__ ksumf)
{
    const int nh = blockIdx.x;
    for (int e = threadIdx.x; e < PKS_; e += 256) {
        const float s = kvf[(size_t)nh * PKS_ + e];
        if (e < KVE_) {
            const int d = e >> 5, v = e & 31;
            short hi, lo; split_bf16(s, hi, lo);
            kvThi[nh * KVE_ + v * D_ + d] = hi;
            kvTlo[nh * KVE_ + v * D_ + d] = lo;
        } else {
            ksumf[nh * D_ + (e - KVE_)] = s;
        }
    }
}

__global__ void la_zero(float* __restrict__ p, int nelem) {
    const int i = blockIdx.x * 256 + threadIdx.x;
    if (i < nelem) p[i] = 0.f;
}

// ---------------- Phase 2: MFMA split-bf16 ----------------
// Wave-task = (16-row tile, h): C[16x32] = phiQ[16x32] @ KV[32x32] via
// 2 v-tiles x 3 split-term mfma_f32_16x16x32_bf16. A-frag: row=lane&15,
// k=(lane>>4)*8+e (any k-permutation cancels: A,B share the mapping).
// D (m89-verified): col=lane&15, row=(lane>>4)*4+reg. dot on fp32 VALU.
__global__ __launch_bounds__(256) void la_phase2(
    const float* __restrict__ queries,
    const short* __restrict__ kvThi, const short* __restrict__ kvTlo,
    const float* __restrict__ ksumf, float* __restrict__ out)
{
    const int t = threadIdx.x, lane = t & 63, w = t >> 6;
    const int wt = blockIdx.x * 4 + w;      // 0..32767
    const int h  = wt & 7;
    const int rt = wt >> 3;                 // 16-row tile id, 0..4095
    const size_t rowg0 = (size_t)rt * 16;   // global (n,l)-row base
    const int n = (int)(rowg0 >> 13);
    const int nh = n * 8 + h;
    const int row_l = lane & 15;            // A-row / B-col
    const int kg    = lane >> 4;            // k-group: k = kg*8 + e

    // ---- A: load 8 fp32 q, phi, keep fp32 for dot, split to bf16 hi/lo ----
    const float* qp = queries + (rowg0 + row_l) * 256 + h * D_ + kg * 8;
    float qa[8];
    {
        const float4 qA = *(const float4*)(qp);
        const float4 qB = *(const float4*)(qp + 4);
        qa[0] = phi_f(qA.x); qa[1] = phi_f(qA.y); qa[2] = phi_f(qA.z); qa[3] = phi_f(qA.w);
        qa[4] = phi_f(qB.x); qa[5] = phi_f(qB.y); qa[6] = phi_f(qB.z); qa[7] = phi_f(qB.w);
    }
    short8 ahi, alo;
#pragma unroll
    for (int e = 0; e < 8; ++e) {
        short hs, ls; split_bf16(qa[e], hs, ls);
        ahi[e] = hs; alo[e] = ls;
    }

    // ---- B: one short8 per (vtile, hi/lo) from transposed bf16 KV ----
    const short* bh = kvThi + (size_t)nh * KVE_;
    const short* bl = kvTlo + (size_t)nh * KVE_;
    const short8 bh0 = *(const short8*)(bh + (row_l     ) * D_ + kg * 8);
    const short8 bh1 = *(const short8*)(bh + (row_l + 16) * D_ + kg * 8);
    const short8 bl0 = *(const short8*)(bl + (row_l     ) * D_ + kg * 8);
    const short8 bl1 = *(const short8*)(bl + (row_l + 16) * D_ + kg * 8);

    // ---- 6 MFMAs: C = Alo*Bhi + Ahi*Blo + Ahi*Bhi (fp32 accum) ----
    f32x4 c0 = {0.f, 0.f, 0.f, 0.f}, c1 = {0.f, 0.f, 0.f, 0.f};
    c0 = __builtin_amdgcn_mfma_f32_16x16x32_bf16(alo, bh0, c0, 0, 0, 0);
    c0 = __builtin_amdgcn_mfma_f32_16x16x32_bf16(ahi, bl0, c0, 0, 0, 0);
    c0 = __builtin_amdgcn_mfma_f32_16x16x32_bf16(ahi, bh0, c0, 0, 0, 0);
    c1 = __builtin_amdgcn_mfma_f32_16x16x32_bf16(alo, bh1, c1, 0, 0, 0);
    c1 = __builtin_amdgcn_mfma_f32_16x16x32_bf16(ahi, bl1, c1, 0, 0, 0);
    c1 = __builtin_amdgcn_mfma_f32_16x16x32_bf16(ahi, bh1, c1, 0, 0, 0);

    // ---- dot = phiQ . Ksum in fp32; reduce the 4 k-groups per row ----
    const float* ksp = ksumf + nh * D_ + kg * 8;
    float dt;
    {
        const float4 kA = *(const float4*)(ksp);
        const float4 kB = *(const float4*)(ksp + 4);
        dt = qa[0] * kA.x;
        dt = fmaf(qa[1], kA.y, dt); dt = fmaf(qa[2], kA.z, dt);
        dt = fmaf(qa[3], kA.w, dt); dt = fmaf(qa[4], kB.x, dt);
        dt = fmaf(qa[5], kB.y, dt); dt = fmaf(qa[6], kB.z, dt);
        dt = fmaf(qa[7], kB.w, dt);
    }
    dt += __shfl_xor(dt, 16);
    dt += __shfl_xor(dt, 32);   // all lanes now hold dot[row_l]

    // ---- normalize + store: row' = kg*4 + r, col = row_l (m89 layout) ----
    float* ob = out + rowg0 * 256 + h * D_ + row_l;
#pragma unroll
    for (int r = 0; r < 4; ++r) {
        const int rowp = kg * 4 + r;
        const float drow = __shfl(dt, rowp);          // lane rowp holds dot[rowp]
        const float z = __builtin_amdgcn_rcpf(drow + 1e-6f);
        ob[(size_t)rowp * 256]      = c0[r] * z;
        ob[(size_t)rowp * 256 + 16] = c1[r] * z;
    }
}

extern "C" void kernel_launch(void* const* d_in, const int* in_sizes, int n_in,
                              void* d_out, int out_size, void* d_ws, size_t ws_size,
                              hipStream_t stream)
{
    const float* queries = (const float*)d_in[0];
    const float* keys    = (const float*)d_in[1];
    const float* values  = (const float*)d_in[2];
    float* out = (float*)d_out;
    float* ws  = (float*)d_ws;

    const size_t partial_elems = (size_t)NH_ * CHUNKS_ * PKS_; // 2,162,688 floats
    const size_t split_elems   = (size_t)NH_ * KVE_;           // per hi/lo, in shorts
    const size_t split_floats  = split_elems / 2;              // 32,768 float-slots each
    const size_t ksum_floats   = (size_t)NH_ * D_;             // 2,048
    const dim3 blk(256);
    const int p2_blocks = (N_ * L_ * H_) / 16 / 4;             // 8192

    if (ws_size >= (partial_elems + 2 * split_floats + ksum_floats) * sizeof(float)) {
        // deterministic two-stage reduction + split-bf16 conversion
        float* partials = ws;
        short* kvThi = (short*)(ws + partial_elems);
        short* kvTlo = kvThi + split_elems;
        float* ksumf = (float*)(kvTlo + split_elems);
        la_phase1<false><<<dim3(NH_, CHUNKS_), blk, 0, stream>>>(keys, values, partials);
        la_reduce<<<dim3(NH_), blk, 0, stream>>>(partials, kvThi, kvTlo, ksumf);
        la_phase2<<<dim3(p2_blocks), blk, 0, stream>>>(queries, kvThi, kvTlo, ksumf, out);
    } else {
        // fallback: atomic accumulation into zeroed kvf, then convert
        float* kvf = ws;
        short* kvThi = (short*)(ws + (size_t)NH_ * PKS_);
        short* kvTlo = kvThi + split_elems;
        float* ksumf = (float*)(kvTlo + split_elems);
        const int nz = (int)((size_t)NH_ * PKS_);
        la_zero<<<dim3((nz + 255) / 256), blk, 0, stream>>>(kvf, nz);
        la_phase1<true><<<dim3(NH_, CHUNKS_), blk, 0, stream>>>(keys, values, kvf);
        la_convert<<<dim3(NH_), blk, 0, stream>>>(kvf, kvThi, kvTlo, ksumf);
        la_phase2<<<dim3(p2_blocks), blk, 0, stream>>>(queries, kvThi, kvTlo, ksumf, out);
    }
}

// Round 12
// 62.834 us; speedup vs baseline: 1.5733x; 1.2760x over previous
//
#include <hip/hip_runtime.h>
#include <hip/hip_bf16.h>

// Linear attention, fp32. N=8, L=S=8192, H=8, D=Dv=32.
// out[n,l,h,v] = (sum_d phiQ[l,d]*KV[d][v]) * 1/(sum_d phiQ[l,d]*Ksum[d] + 1e-6)
// where KV[d][v] = sum_s phiK[s,d]*values[s,v]  (the /S and *S of the reference
// cancel exactly: S is a power of two).
//
// R12: phase1 moved to MFMA too. R1-R11 showed every per-lane-VALU phase1
// lands ~57-64us (LDS-issue or LDS-BW bound: V-fragment needs 1024B/instr).
// KV accumulation is a 32x32x8192 GEMM per (n,h): C = phiK^T . V via
// mfma_f32_16x16x32_bf16, split-bf16 3-term (KV err ~1e-5). K/V staged
// TRANSPOSED and hi|lo-PACKED per u32 (one b128 read = both halves of a
// fragment), row stride 76 u32 (16B-aligned, banks spread). One barrier per
// 64-s tile, register double-buffer. Ksum exact fp32 during staging.
// Phase2 = R10/R11's split-bf16 MFMA (passed twice, absmax 2.4e-4).

#define N_      8
#define L_      8192
#define S_      8192
#define H_      8
#define D_      32
#define NH_     64            // N*H
#define CH1_    16            // phase-1 s-chunks per (n,h)
#define SPC1_   512           // s per phase-1 block
#define TILEP_  76            // packed-u32 LDS row stride (16B-aligned, 12-pad)
#define KVE_    (D_ * D_)     // 1024
#define PKS_    (KVE_ + D_)   // 1056 floats: KV + Ksum

typedef short short8 __attribute__((ext_vector_type(8)));
typedef float f32x4  __attribute__((ext_vector_type(4)));

__device__ __forceinline__ float phi_f(float x) {
    // elu(x)+1 : x>0 -> x+1 ; else exp(x)
    return x > 0.f ? x + 1.f : __expf(x);
}

__device__ __forceinline__ void split_bf16(float x, short& hi, short& lo) {
    __hip_bfloat16 hb = __float2bfloat16(x);        // RNE
    const float xh = __bfloat162float(hb);
    __hip_bfloat16 lb = __float2bfloat16(x - xh);
    __builtin_memcpy(&hi, &hb, 2);
    __builtin_memcpy(&lo, &lb, 2);
}

__device__ __forceinline__ unsigned packsplit(float x) {
    short hi, lo; split_bf16(x, hi, lo);
    return ((unsigned)(unsigned short)hi << 16) | (unsigned)(unsigned short)lo;
}

// 8 packed u32 (k-elements 0..7) -> hi/lo bf16 short8 fragments
__device__ __forceinline__ void unpack8(uint4 p0, uint4 p1, short8& hi, short8& lo) {
    union { unsigned u[4]; short8 s; } H, L;
    const unsigned q[8] = {p0.x, p0.y, p0.z, p0.w, p1.x, p1.y, p1.z, p1.w};
#pragma unroll
    for (int i = 0; i < 4; ++i) {
        H.u[i] = (q[2 * i + 1] & 0xffff0000u) | (q[2 * i] >> 16);
        L.u[i] = (q[2 * i + 1] << 16) | (q[2 * i] & 0xffffu);
    }
    hi = H.s; lo = L.s;
}

// ---------------- Phase 1: C[32d x 32v] = phiK^T . V per (n,h,chunk) --------
// 4 waves = 4 C-tiles (dt,vt). Staging: thread (row8=t>>3, c4=t&7) loads K/V
// float4 of rows {row8, row8+32}, phi+split+pack, writes TRANSPOSED:
// kP[d][s], vP[v][s] (packed u32). Fragments: lane(row_l,kg) reads 2x b128.
template <bool ATOMIC>
__global__ __launch_bounds__(256) void la_phase1(
    const float* __restrict__ keys, const float* __restrict__ values,
    float* __restrict__ outp /* ATOMIC ? kvfinal[NH][PKS] : partials[NH][CH1][PKS] */)
{
    __shared__ unsigned kP[2][32][TILEP_];
    __shared__ unsigned vP[2][32][TILEP_];
    __shared__ float red_ks[4][8][4];
    const int nh = blockIdx.x, chunk = blockIdx.y;
    const int n = nh >> 3, h = nh & 7;
    const int t = threadIdx.x, lane = t & 63, w = t >> 6;
    const int row8 = t >> 3;           // 0..31 (s-row within tile half)
    const int c4   = t & 7;            // float4 column
    const int row_l = lane & 15, kg = lane >> 4;
    const int dt = w >> 1, vt = w & 1; // wave's C-tile
    const float* kb = keys   + ((size_t)n * S_) * 256 + h * 32 + (c4 << 2);
    const float* vb = values + ((size_t)n * S_) * 256 + h * 32 + (c4 << 2);
    const int s0 = chunk * SPC1_;

    float ks4[4] = {0.f, 0.f, 0.f, 0.f};
    f32x4 cacc = {0.f, 0.f, 0.f, 0.f};
    float4 Lka, Lkb, Lva, Lvb;

    auto LOADT = [&](int tb) {
        const size_t g0 = ((size_t)(s0 + (tb << 6) + row8)) << 8;
        const size_t g1 = ((size_t)(s0 + (tb << 6) + row8 + 32)) << 8;
        Lka = *(const float4*)(kb + g0);
        Lkb = *(const float4*)(kb + g1);
        Lva = *(const float4*)(vb + g0);
        Lvb = *(const float4*)(vb + g1);
    };
    auto PROCT = [&](int buf) {
        const float f0[4] = {phi_f(Lka.x), phi_f(Lka.y), phi_f(Lka.z), phi_f(Lka.w)};
        const float f1[4] = {phi_f(Lkb.x), phi_f(Lkb.y), phi_f(Lkb.z), phi_f(Lkb.w)};
        const float g0[4] = {Lva.x, Lva.y, Lva.z, Lva.w};
        const float g1[4] = {Lvb.x, Lvb.y, Lvb.z, Lvb.w};
#pragma unroll
        for (int j = 0; j < 4; ++j) {
            ks4[j] += f0[j] + f1[j];
            const int dv = (c4 << 2) + j;
            kP[buf][dv][row8]      = packsplit(f0[j]);
            kP[buf][dv][row8 + 32] = packsplit(f1[j]);
            vP[buf][dv][row8]      = packsplit(g0[j]);
            vP[buf][dv][row8 + 32] = packsplit(g1[j]);
        }
    };
    auto COMPT = [&](int buf) {
#pragma unroll
        for (int sh = 0; sh < 2; ++sh) {
            const unsigned* ap = &kP[buf][(dt << 4) + row_l][(sh << 5) + (kg << 3)];
            const unsigned* bp = &vP[buf][(vt << 4) + row_l][(sh << 5) + (kg << 3)];
            const uint4 a0 = *(const uint4*)ap, a1 = *(const uint4*)(ap + 4);
            const uint4 b0 = *(const uint4*)bp, b1 = *(const uint4*)(bp + 4);
            short8 ahi, alo, bhi, blo;
            unpack8(a0, a1, ahi, alo);
            unpack8(b0, b1, bhi, blo);
            cacc = __builtin_amdgcn_mfma_f32_16x16x32_bf16(ahi, bhi, cacc, 0, 0, 0);
            cacc = __builtin_amdgcn_mfma_f32_16x16x32_bf16(ahi, blo, cacc, 0, 0, 0);
            cacc = __builtin_amdgcn_mfma_f32_16x16x32_bf16(alo, bhi, cacc, 0, 0, 0);
        }
    };

    LOADT(0);
    PROCT(0);
    __syncthreads();
#pragma unroll
    for (int tb = 0; tb < 8; ++tb) {
        const int cur = tb & 1;
        if (tb < 7) LOADT(tb + 1);       // loads in flight under compute (T14)
        COMPT(cur);
        if (tb < 7) PROCT(cur ^ 1);      // waits vmcnt, writes other buffer
        __syncthreads();
    }

    // ksum: butterfly over lane bits 3..5 (8 same-c4 lanes), then cross-wave
#pragma unroll
    for (int j = 0; j < 4; ++j) {
        float x = ks4[j];
        x += __shfl_xor(x, 8);
        x += __shfl_xor(x, 16);
        x += __shfl_xor(x, 32);
        ks4[j] = x;
    }
    if (lane < 8) {
#pragma unroll
        for (int j = 0; j < 4; ++j) red_ks[w][lane][j] = ks4[j];
    }
    __syncthreads();

    if (ATOMIC) {
        float* p = outp + (size_t)nh * PKS_;
#pragma unroll
        for (int r = 0; r < 4; ++r) {
            const int dd = (dt << 4) + (kg << 2) + r;   // D row = (lane>>4)*4+reg
            const int vv = (vt << 4) + row_l;           // D col = lane&15
            atomicAdd(&p[dd * D_ + vv], cacc[r]);
        }
        if (t < 32) {
            const float s = red_ks[0][t >> 2][t & 3] + red_ks[1][t >> 2][t & 3]
                          + red_ks[2][t >> 2][t & 3] + red_ks[3][t >> 2][t & 3];
            atomicAdd(&p[KVE_ + t], s);
        }
    } else {
        float* p = outp + ((size_t)nh * CH1_ + chunk) * PKS_;
#pragma unroll
        for (int r = 0; r < 4; ++r) {
            const int dd = (dt << 4) + (kg << 2) + r;
            const int vv = (vt << 4) + row_l;
            p[dd * D_ + vv] = cacc[r];
        }
        if (t < 32) {
            p[KVE_ + t] = red_ks[0][t >> 2][t & 3] + red_ks[1][t >> 2][t & 3]
                        + red_ks[2][t >> 2][t & 3] + red_ks[3][t >> 2][t & 3];
        }
    }
}

// ---- Phase 1b: deterministic 16-way reduce + split-bf16 transpose ----
// kvThi/kvTlo: [NH][32v][32d] bf16 (transposed so phase2 B-frag is one b128);
// ksumf: [NH][32] fp32 for the fp32 dot.
__global__ __launch_bounds__(256) void la_reduce(
    const float* __restrict__ partials,
    short* __restrict__ kvThi, short* __restrict__ kvTlo,
    float* __restrict__ ksumf)
{
    const int nh = blockIdx.x;
    for (int e = threadIdx.x; e < PKS_; e += 256) {
        const float* p = partials + (size_t)nh * CH1_ * PKS_ + e;
        float s = 0.f;
#pragma unroll
        for (int c = 0; c < CH1_; ++c) s += p[(size_t)c * PKS_];
        if (e < KVE_) {
            const int d = e >> 5, v = e & 31;
            short hi, lo; split_bf16(s, hi, lo);
            kvThi[nh * KVE_ + v * D_ + d] = hi;
            kvTlo[nh * KVE_ + v * D_ + d] = lo;
        } else {
            ksumf[nh * D_ + (e - KVE_)] = s;
        }
    }
}

// atomic-path variant: same split/transpose from a finished kvf buffer
__global__ __launch_bounds__(256) void la_convert(
    const float* __restrict__ kvf,
    short* __restrict__ kvThi, short* __restrict__ kvTlo,
    float* __restrict__ ksumf)
{
    const int nh = blockIdx.x;
    for (int e = threadIdx.x; e < PKS_; e += 256) {
        const float s = kvf[(size_t)nh * PKS_ + e];
        if (e < KVE_) {
            const int d = e >> 5, v = e & 31;
            short hi, lo; split_bf16(s, hi, lo);
            kvThi[nh * KVE_ + v * D_ + d] = hi;
            kvTlo[nh * KVE_ + v * D_ + d] = lo;
        } else {
            ksumf[nh * D_ + (e - KVE_)] = s;
        }
    }
}

__global__ void la_zero(float* __restrict__ p, int nelem) {
    const int i = blockIdx.x * 256 + threadIdx.x;
    if (i < nelem) p[i] = 0.f;
}

// ---------------- Phase 2: MFMA split-bf16 ----------------
// Wave-task = (16-row tile, h): C[16x32] = phiQ[16x32] @ KV[32x32] via
// 2 v-tiles x 3 split-term mfma_f32_16x16x32_bf16. A-frag: row=lane&15,
// k=(lane>>4)*8+e (any k-permutation cancels: A,B share the mapping).
// D (m89-verified): col=lane&15, row=(lane>>4)*4+reg. dot on fp32 VALU.
__global__ __launch_bounds__(256) void la_phase2(
    const float* __restrict__ queries,
    const short* __restrict__ kvThi, const short* __restrict__ kvTlo,
    const float* __restrict__ ksumf, float* __restrict__ out)
{
    const int t = threadIdx.x, lane = t & 63, w = t >> 6;
    const int wt = blockIdx.x * 4 + w;      // 0..32767
    const int h  = wt & 7;
    const int rt = wt >> 3;                 // 16-row tile id, 0..4095
    const size_t rowg0 = (size_t)rt * 16;   // global (n,l)-row base
    const int n = (int)(rowg0 >> 13);
    const int nh = n * 8 + h;
    const int row_l = lane & 15;            // A-row / B-col
    const int kg    = lane >> 4;            // k-group: k = kg*8 + e

    // ---- A: load 8 fp32 q, phi, keep fp32 for dot, split to bf16 hi/lo ----
    const float* qp = queries + (rowg0 + row_l) * 256 + h * D_ + kg * 8;
    float qa[8];
    {
        const float4 qA = *(const float4*)(qp);
        const float4 qB = *(const float4*)(qp + 4);
        qa[0] = phi_f(qA.x); qa[1] = phi_f(qA.y); qa[2] = phi_f(qA.z); qa[3] = phi_f(qA.w);
        qa[4] = phi_f(qB.x); qa[5] = phi_f(qB.y); qa[6] = phi_f(qB.z); qa[7] = phi_f(qB.w);
    }
    short8 ahi, alo;
#pragma unroll
    for (int e = 0; e < 8; ++e) {
        short hs, ls; split_bf16(qa[e], hs, ls);
        ahi[e] = hs; alo[e] = ls;
    }

    // ---- B: one short8 per (vtile, hi/lo) from transposed bf16 KV ----
    const short* bh = kvThi + (size_t)nh * KVE_;
    const short* bl = kvTlo + (size_t)nh * KVE_;
    const short8 bh0 = *(const short8*)(bh + (row_l     ) * D_ + kg * 8);
    const short8 bh1 = *(const short8*)(bh + (row_l + 16) * D_ + kg * 8);
    const short8 bl0 = *(const short8*)(bl + (row_l     ) * D_ + kg * 8);
    const short8 bl1 = *(const short8*)(bl + (row_l + 16) * D_ + kg * 8);

    // ---- 6 MFMAs: C = Alo*Bhi + Ahi*Blo + Ahi*Bhi (fp32 accum) ----
    f32x4 c0 = {0.f, 0.f, 0.f, 0.f}, c1 = {0.f, 0.f, 0.f, 0.f};
    c0 = __builtin_amdgcn_mfma_f32_16x16x32_bf16(alo, bh0, c0, 0, 0, 0);
    c0 = __builtin_amdgcn_mfma_f32_16x16x32_bf16(ahi, bl0, c0, 0, 0, 0);
    c0 = __builtin_amdgcn_mfma_f32_16x16x32_bf16(ahi, bh0, c0, 0, 0, 0);
    c1 = __builtin_amdgcn_mfma_f32_16x16x32_bf16(alo, bh1, c1, 0, 0, 0);
    c1 = __builtin_amdgcn_mfma_f32_16x16x32_bf16(ahi, bl1, c1, 0, 0, 0);
    c1 = __builtin_amdgcn_mfma_f32_16x16x32_bf16(ahi, bh1, c1, 0, 0, 0);

    // ---- dot = phiQ . Ksum in fp32; reduce the 4 k-groups per row ----
    const float* ksp = ksumf + nh * D_ + kg * 8;
    float dt;
    {
        const float4 kA = *(const float4*)(ksp);
        const float4 kB = *(const float4*)(ksp + 4);
        dt = qa[0] * kA.x;
        dt = fmaf(qa[1], kA.y, dt); dt = fmaf(qa[2], kA.z, dt);
        dt = fmaf(qa[3], kA.w, dt); dt = fmaf(qa[4], kB.x, dt);
        dt = fmaf(qa[5], kB.y, dt); dt = fmaf(qa[6], kB.z, dt);
        dt = fmaf(qa[7], kB.w, dt);
    }
    dt += __shfl_xor(dt, 16);
    dt += __shfl_xor(dt, 32);   // all lanes now hold dot[row_l]

    // ---- normalize + store: row' = kg*4 + r, col = row_l (m89 layout) ----
    float* ob = out + rowg0 * 256 + h * D_ + row_l;
#pragma unroll
    for (int r = 0; r < 4; ++r) {
        const int rowp = kg * 4 + r;
        const float drow = __shfl(dt, rowp);          // lane rowp holds dot[rowp]
        const float z = __builtin_amdgcn_rcpf(drow + 1e-6f);
        ob[(size_t)rowp * 256]      = c0[r] * z;
        ob[(size_t)rowp * 256 + 16] = c1[r] * z;
    }
}

extern "C" void kernel_launch(void* const* d_in, const int* in_sizes, int n_in,
                              void* d_out, int out_size, void* d_ws, size_t ws_size,
                              hipStream_t stream)
{
    const float* queries = (const float*)d_in[0];
    const float* keys    = (const float*)d_in[1];
    const float* values  = (const float*)d_in[2];
    float* out = (float*)d_out;
    float* ws  = (float*)d_ws;

    const size_t partial_elems = (size_t)NH_ * CH1_ * PKS_;    // 1,081,344 floats
    const size_t split_elems   = (size_t)NH_ * KVE_;           // per hi/lo, in shorts
    const size_t split_floats  = split_elems / 2;              // 32,768 float-slots each
    const size_t ksum_floats   = (size_t)NH_ * D_;             // 2,048
    const dim3 blk(256);
    const int p2_blocks = (N_ * L_ * H_) / 16 / 4;             // 8192

    if (ws_size >= (partial_elems + 2 * split_floats + ksum_floats) * sizeof(float)) {
        // deterministic two-stage reduction + split-bf16 conversion
        float* partials = ws;
        short* kvThi = (short*)(ws + partial_elems);
        short* kvTlo = kvThi + split_elems;
        float* ksumf = (float*)(kvTlo + split_elems);
        la_phase1<false><<<dim3(NH_, CH1_), blk, 0, stream>>>(keys, values, partials);
        la_reduce<<<dim3(NH_), blk, 0, stream>>>(partials, kvThi, kvTlo, ksumf);
        la_phase2<<<dim3(p2_blocks), blk, 0, stream>>>(queries, kvThi, kvTlo, ksumf, out);
    } else {
        // fallback: atomic accumulation into zeroed kvf, then convert
        float* kvf = ws;
        short* kvThi = (short*)(ws + (size_t)NH_ * PKS_);
        short* kvTlo = kvThi + split_elems;
        float* ksumf = (float*)(kvTlo + split_elems);
        const int nz = (int)((size_t)NH_ * PKS_);
        la_zero<<<dim3((nz + 255) / 256), blk, 0, stream>>>(kvf, nz);
        la_phase1<true><<<dim3(NH_, CH1_), blk, 0, stream>>>(keys, values, kvf);
        la_convert<<<dim3(NH_), blk, 0, stream>>>(kvf, kvThi, kvTlo, ksumf);
        la_phase2<<<dim3(p2_blocks), blk, 0, stream>>>(queries, kvThi, kvTlo, ksumf, out);
    }
}